// Round 9
// baseline (262.862 us; speedup 1.0000x reference)
//
#include <hip/hip_runtime.h>
#include <math.h>

#define NS   16
#define HH   512
#define WW   512
#define HW   (HH*WW)
#define TOPK 13107
#define NBIN 1024

// ---- ws word offsets. NO ATOMICS EVER TARGET d_ws (measured 100+us stalls r1/r2).
// ---- NO cooperative/persistent kernel (measured 1.1ms effective 263 GB/s, r5).
// ---- NO ballot-leader aggregation for smooth value-domain bins (r6: 157us k_dark).
// ---- Dispatch boundaries ~2us each (r7->r8); keep dispatch count minimal.
#define O_O1   0        // [16][7] squashed o1 params   (written k_sel, read k_main)
#define O_O2   112      // [16][4] softmax weights
#define O_DEN  176      // [16]    sum(o2)+0.001
#define O_A    320      // [16][3] atmospheric light    (written k_sel)
#define O_MMP  512      // [48][512] per-tile min(0:256)/max(256:512) partials
#define O_DARK 33280    // [16*512*512] f32 dark channel

// ---- d_out scratch (words; consumed by k_sel before k_main overwrites out):
//   hist = out + 16HW : [16][1024][4] = {cnt u32, s0 f32, s1 f32, s2 f32} per bin
//   (atomics OK here — d_out, measured fast r2-r4)

// Gaussian weights phi/(sum+0.001), hardcoded (double-derived; ref fp32 diff ~1e-8)
#define G0 0.054466787f
#define G1 0.244103071f
#define G2 0.402457854f

__device__ __forceinline__ float tanh01(float v) { return tanhf(v)*0.5f + 0.5f; }
__device__ __forceinline__ float clamp01(float v) { return fminf(fmaxf(v, 0.0f), 1.0f); }
__device__ __forceinline__ int dark_bin(float v) {
  int b = (int)(v * (float)NBIN);
  return b > (NBIN-1) ? (NBIN-1) : (b < 0 ? 0 : b);
}

// ---------------- zero histogram (16*1024*4 = 65536 words) ----------------
__global__ void k_zero(unsigned* __restrict__ hist) {
  int i = blockIdx.x * 256 + threadIdx.x;       // 16384 uint4
  uint4 z; z.x = 0u; z.y = 0u; z.z = 0u; z.w = 0u;
  ((uint4*)hist)[i] = z;
}

// ---------------- fused minc + 15x15 box filter + binned {cnt,Σx} ----------------
// block: 64x32 dark tile. grid (8,16,16).
__global__ void __launch_bounds__(256)
k_dark(const float* __restrict__ x, float* __restrict__ wsf, unsigned* __restrict__ hist) {
  __shared__ __align__(16) float sm[7040];   // union(minc[3680], bins[4096]) + hsum[2944]
  float* minc = sm;
  unsigned* bins = (unsigned*)sm;            // [1024][4] {cnt,s0,s1,s2}
  float* binsf = sm;
  float* hsum = sm + 4096;
  int tid = threadIdx.x;
  int w0 = blockIdx.x * 64, h0 = blockIdx.y * 32, n = blockIdx.z;
  const float* xb = x + (size_t)n*3*HW;

  // stage minc rows [h0-7,h0+39) cols [w0-8,w0+72)
  bool interior = (w0 >= 8) && (w0 + 72 <= WW) && (h0 >= 7) && (h0 + 39 <= HH);
  if (interior) {
    for (int i = tid; i < 46*20; i += 256) {
      int r = i / 20, q = i - r*20;
      size_t o = (size_t)(h0 - 7 + r)*WW + (w0 - 8 + 4*q);
      float4 a = *(const float4*)&xb[o];
      float4 b = *(const float4*)&xb[HW + o];
      float4 c = *(const float4*)&xb[2*HW + o];
      float4 v;
      v.x = fminf(fminf(a.x,b.x),c.x); v.y = fminf(fminf(a.y,b.y),c.y);
      v.z = fminf(fminf(a.z,b.z),c.z); v.w = fminf(fminf(a.w,b.w),c.w);
      *(float4*)&minc[r*80 + 4*q] = v;
    }
  } else {
    for (int i = tid; i < 46*20; i += 256) {
      int r = i / 20, q = i - r*20;
      int hm = h0 - 7 + r, wc = w0 - 8 + 4*q;
      float4 v; v.x = 0.f; v.y = 0.f; v.z = 0.f; v.w = 0.f;
      if (hm >= 0 && hm < HH && wc >= 0 && wc < WW) {
        size_t o = (size_t)hm*WW + wc;
        float4 a = *(const float4*)&xb[o];
        float4 b = *(const float4*)&xb[HW + o];
        float4 c = *(const float4*)&xb[2*HW + o];
        v.x = fminf(fminf(a.x,b.x),c.x); v.y = fminf(fminf(a.y,b.y),c.y);
        v.z = fminf(fminf(a.z,b.z),c.z); v.w = fminf(fminf(a.w,b.w),c.w);
      }
      *(float4*)&minc[r*80 + 4*q] = v;
    }
  }
  __syncthreads();
  // horizontal 15-tap sum
  for (int i = tid; i < 46*16; i += 256) {
    int r = i >> 4, c4 = (i & 15) * 4;
    const float4* mr = (const float4*)&minc[r*80];
    int qb = c4 >> 2;
    float m[20];
    #pragma unroll
    for (int t = 0; t < 5; ++t) {
      float4 v = mr[qb + t];
      m[4*t] = v.x; m[4*t+1] = v.y; m[4*t+2] = v.z; m[4*t+3] = v.w;
    }
    float s = 0.f;
    #pragma unroll
    for (int j = 1; j <= 15; ++j) s += m[j];
    float4 o;
    o.x = s; s += m[16] - m[1];
    o.y = s; s += m[17] - m[2];
    o.z = s; s += m[18] - m[3];
    o.w = s;
    *(float4*)&hsum[r*64 + c4] = o;
  }
  __syncthreads();
  for (int i = tid; i < 4096; i += 256) bins[i] = 0u;   // minc dead; reuse as bins
  __syncthreads();
  // vertical 15-tap sliding sum -> dark; accumulate {cnt, Σx0, Σx1, Σx2} per bin
  {
    int c = tid & 63, ty = tid >> 6, r0 = ty * 8;
    float s = 0.f;
    #pragma unroll
    for (int j = 0; j < 15; ++j) s += hsum[(r0 + j)*64 + c];
    float* dk = wsf + O_DARK + (size_t)n*HW;
    #pragma unroll
    for (int i = 0; i < 8; ++i) {
      int r = r0 + i;
      size_t po = (size_t)(h0 + r)*WW + w0 + c;
      float v = s * (1.0f/225.0f);
      dk[po] = v;
      int b = dark_bin(v);
      float x0v = xb[po], x1v = xb[HW + po], x2v = xb[2*HW + po];  // L1/L2-hot
      atomicAdd(&bins[b*4], 1u);
      atomicAdd(&binsf[b*4+1], x0v);
      atomicAdd(&binsf[b*4+2], x1v);
      atomicAdd(&binsf[b*4+3], x2v);
      if (i < 7) s += hsum[(r + 15)*64 + c] - hsum[r*64 + c];
    }
  }
  __syncthreads();
  unsigned* gh = hist + n*NBIN*4;
  for (int b = tid; b < NBIN; b += 256) {
    unsigned cnt = bins[b*4];
    if (cnt) {
      atomicAdd(&gh[b*4], cnt);
      atomicAdd((float*)&gh[b*4+1], binsf[b*4+1]);
      atomicAdd((float*)&gh[b*4+2], binsf[b*4+2]);
      atomicAdd((float*)&gh[b*4+3], binsf[b*4+3]);
    }
  }
}

// ---------------- select + A computation + param squashing (16 blocks) ----------------
__global__ void __launch_bounds__(256)
k_sel(const unsigned* __restrict__ hist, float* __restrict__ wsf,
      const float* __restrict__ o1, const float* __restrict__ o2) {
  __shared__ float s0s[NBIN], s1s[NBIN], s2s[NBIN];
  __shared__ unsigned cnts[NBIN];
  __shared__ unsigned partial[256];
  __shared__ int sh_bsel; __shared__ float sh_kn;
  __shared__ float red[4][3];
  int n = blockIdx.x, tid = threadIdx.x;
  const uint4* g4 = (const uint4*)(hist + n*NBIN*4);
  unsigned ps = 0;
  #pragma unroll
  for (int k = 0; k < 4; ++k) {
    int b = tid*4 + k;
    uint4 v = g4[b];
    cnts[b] = v.x;
    s0s[b] = __uint_as_float(v.y);
    s1s[b] = __uint_as_float(v.z);
    s2s[b] = __uint_as_float(v.w);
    ps += v.x;
  }
  partial[tid] = ps;
  __syncthreads();
  if (tid == 0) {
    const unsigned K = TOPK;
    unsigned cum = 0; int bsel = 0;
    for (int t = 255; t >= 0; --t) {
      if (cum + partial[t] >= K) {
        bsel = t*4;
        for (int b = t*4 + 3; b >= t*4; --b) {
          if (cum + cnts[b] >= K) { bsel = b; break; }
          cum += cnts[b];
        }
        break;
      }
      cum += partial[t];
    }
    sh_bsel = bsel; sh_kn = (float)(K - cum);
  }
  __syncthreads();
  int bsel = sh_bsel;
  float a0 = 0.f, a1 = 0.f, a2 = 0.f;
  for (int b = tid; b < NBIN; b += 256)
    if (b > bsel) { a0 += s0s[b]; a1 += s1s[b]; a2 += s2s[b]; }
  #pragma unroll
  for (int off = 32; off; off >>= 1) {
    a0 += __shfl_down(a0, off); a1 += __shfl_down(a1, off); a2 += __shfl_down(a2, off);
  }
  int wave = tid >> 6, lane = tid & 63;
  if (lane == 0) { red[wave][0] = a0; red[wave][1] = a1; red[wave][2] = a2; }
  __syncthreads();
  if (tid == 0) {
    a0 = red[0][0]+red[1][0]+red[2][0]+red[3][0];
    a1 = red[0][1]+red[1][1]+red[2][1]+red[3][1];
    a2 = red[0][2]+red[1][2]+red[2][2]+red[3][2];
    float kn = sh_kn;
    float ce = fmaxf((float)cnts[bsel], 1.0f);
    wsf[O_A + n*3 + 0] = (a0 + kn*(s0s[bsel]/ce)) * (1.0f/(float)TOPK);
    wsf[O_A + n*3 + 1] = (a1 + kn*(s1s[bsel]/ce)) * (1.0f/(float)TOPK);
    wsf[O_A + n*3 + 2] = (a2 + kn*(s2s[bsel]/ce)) * (1.0f/(float)TOPK);
    // param squashing (plain stores to ws)
    wsf[O_O1+n*7+0] = tanh01(o1[n*7+0])*0.25f + 1.0f;
    wsf[O_O1+n*7+1] = tanh01(o1[n*7+1])*0.9f  + 0.1f;
    wsf[O_O1+n*7+2] = tanh01(o1[n*7+2])*2.0f;
    wsf[O_O1+n*7+3] = tanh01(o1[n*7+3]);
    wsf[O_O1+n*7+4] = tanh01(o1[n*7+4])*0.1f + 0.95f;
    wsf[O_O1+n*7+5] = tanh01(o1[n*7+5])*0.1f + 0.95f;
    wsf[O_O1+n*7+6] = tanh01(o1[n*7+6])*0.1f + 0.95f;
    float q0 = expf(tanh01(o2[n*4+0]));
    float q1 = expf(tanh01(o2[n*4+1]));
    float q2 = expf(tanh01(o2[n*4+2]));
    float q3 = expf(tanh01(o2[n*4+3]));
    float s = q0+q1+q2+q3;
    q0 /= s; q1 /= s; q2 /= s; q3 /= s;
    wsf[O_O2+n*4+0]=q0; wsf[O_O2+n*4+1]=q1; wsf[O_O2+n*4+2]=q2; wsf[O_O2+n*4+3]=q3;
    wsf[O_DEN+n] = (q0+q1+q2+q3) + 0.001f;
  }
}

// ---------------- fused per-pixel kernel: 3 channels per block ----------------
// grid (8,32,16): 64x16 tile of sample n, channels 0..2 sequentially (dark read once)
__global__ void __launch_bounds__(256)
k_main(const float* __restrict__ x, float* __restrict__ wsf, float* __restrict__ out) {
  __shared__ __align__(16) float xs[20*72];   // rows h0-2..h0+17, cols w0-4..w0+67
  __shared__ __align__(16) float hb[20*64];   // horizontal blur
  __shared__ float rmn[4], rmx[4];
  int tid = threadIdx.x;
  int w0 = blockIdx.x * 64, h0 = blockIdx.y * 16, n = blockIdx.z;
  int r = tid >> 4, c4 = (tid & 15) * 4;
  int wave = tid >> 6, lane = tid & 63;
  int bxy = blockIdx.y * 8 + blockIdx.x;
  float4 dk = *(const float4*)&wsf[O_DARK + (size_t)n*HW + (size_t)(h0+r)*WW + w0 + c4];
  float param = wsf[O_O1 + n*7 + 0];
  float lamda = wsf[O_O1 + n*7 + 2];
  float wpar  = wsf[O_O1 + n*7 + 3];
  float q0 = wsf[O_O2 + n*4 + 0], q1 = wsf[O_O2 + n*4 + 1];
  float q2 = wsf[O_O2 + n*4 + 2], q3 = wsf[O_O2 + n*4 + 3];
  float rden = 1.0f / wsf[O_DEN + n];
  bool interior = (w0 >= 4) && (w0 + 68 <= WW) && (h0 >= 2) && (h0 + 18 <= HH);

  for (int c = 0; c < 3; ++c) {
    int z = n*3 + c;
    const float* xc = x + (size_t)z*HW;
    if (interior) {
      for (int i = tid; i < 360; i += 256) {
        int rr = i / 18, q = i - rr*18;
        *(float4*)&xs[rr*72 + 4*q] =
            *(const float4*)&xc[(size_t)(h0 - 2 + rr)*WW + (w0 - 4 + 4*q)];
      }
    } else {
      for (int i = tid; i < 360; i += 256) {
        int rr = i / 18, q = i - rr*18;
        int gh = h0 - 2 + rr, gw = w0 - 4 + 4*q;
        float4 v; v.x = 0.f; v.y = 0.f; v.z = 0.f; v.w = 0.f;
        if (gh >= 0 && gh < HH && gw >= 0 && gw < WW)
          v = *(const float4*)&xc[(size_t)gh*WW + gw];
        *(float4*)&xs[rr*72 + 4*q] = v;
      }
    }
    __syncthreads();
    for (int i = tid; i < 320; i += 256) {
      int rr = i >> 4, cc4 = (i & 15) * 4;
      const float4* xr = (const float4*)&xs[rr*72];
      int qb = cc4 >> 2;
      float4 A4 = xr[qb], B4 = xr[qb+1], C4 = xr[qb+2];
      float m2=A4.z, m3=A4.w, m4=B4.x, m5=B4.y, m6=B4.z, m7=B4.w, m8=C4.x, m9=C4.y;
      float4 o;
      o.x = G0*(m2+m6) + G1*(m3+m5) + G2*m4;
      o.y = G0*(m3+m7) + G1*(m4+m6) + G2*m5;
      o.z = G0*(m4+m8) + G1*(m5+m7) + G2*m6;
      o.w = G0*(m5+m9) + G1*(m6+m8) + G2*m7;
      *(float4*)&hb[rr*64 + cc4] = o;
    }
    __syncthreads();
    float wb = wsf[O_O1 + n*7 + 4 + c];
    float A  = wsf[O_A + n*3 + c];
    float4 xv = *(const float4*)&xs[(r+2)*72 + c4 + 4];
    float4 b0 = *(const float4*)&hb[(r+0)*64 + c4];
    float4 b1 = *(const float4*)&hb[(r+1)*64 + c4];
    float4 b2 = *(const float4*)&hb[(r+2)*64 + c4];
    float4 b3 = *(const float4*)&hb[(r+3)*64 + c4];
    float4 b4 = *(const float4*)&hb[(r+4)*64 + c4];
    float4 osum;
    float mnv = 3.4e38f, mxv = -3.4e38f;
    #define PIX(OX, XV, B0, B1, B2, B3, B4, DK) { \
      float blur = clamp01(G0*(B0+B4) + G1*(B1+B3) + G2*B2); \
      float x4v = clamp01(XV + lamda*(XV - blur)); \
      float x1v = clamp01(XV * wb); \
      float x2v = clamp01(__expf(param*__logf(XV)) + 0.001f); \
      float tr = 1.0f - wpar*DK; tr = tr > 0.1f ? tr : 0.1f; \
      float x5v = clamp01((XV - A) * __builtin_amdgcn_rcpf(tr + 0.001f) + A); \
      OX = (XV + 0.1f*(q0*x1v + q1*x2v + q2*x4v + q3*x5v)) * rden; \
      mnv = fminf(mnv, OX); mxv = fmaxf(mxv, OX); }
    PIX(osum.x, xv.x, b0.x, b1.x, b2.x, b3.x, b4.x, dk.x)
    PIX(osum.y, xv.y, b0.y, b1.y, b2.y, b3.y, b4.y, dk.y)
    PIX(osum.z, xv.z, b0.z, b1.z, b2.z, b3.z, b4.z, dk.z)
    PIX(osum.w, xv.w, b0.w, b1.w, b2.w, b3.w, b4.w, dk.w)
    #undef PIX
    *(float4*)&out[(size_t)z*HW + (size_t)(h0+r)*WW + w0 + c4] = osum;
    #pragma unroll
    for (int off = 32; off; off >>= 1) {
      mnv = fminf(mnv, __shfl_down(mnv, off));
      mxv = fmaxf(mxv, __shfl_down(mxv, off));
    }
    if (lane == 0) { rmn[wave] = mnv; rmx[wave] = mxv; }
    __syncthreads();   // also protects xs/hb reuse next channel
    if (tid == 0) {
      mnv = fminf(fminf(rmn[0], rmn[1]), fminf(rmn[2], rmn[3]));
      mxv = fmaxf(fmaxf(rmx[0], rmx[1]), fmaxf(rmx[2], rmx[3]));
      wsf[O_MMP + z*512 + bxy]       = mnv;   // plain stores to ws
      wsf[O_MMP + z*512 + 256 + bxy] = mxv;
    }
  }
}

// ---------------- fused min/max fold head + streaming normalization ----------------
__global__ void __launch_bounds__(256)
k_norm(float* __restrict__ out, const float* __restrict__ wsf) {
  __shared__ float rmn[4], rmx[4];
  int tid = threadIdx.x;
  int nc = blockIdx.x >> 5;          // 32 blocks per (n,c), 2048 f4 each
  int sub = blockIdx.x & 31;
  float mn = wsf[O_MMP + nc*512 + tid];
  float mx = wsf[O_MMP + nc*512 + 256 + tid];
  #pragma unroll
  for (int off = 32; off; off >>= 1) {
    mn = fminf(mn, __shfl_down(mn, off));
    mx = fmaxf(mx, __shfl_down(mx, off));
  }
  int wave = tid >> 6, lane = tid & 63;
  if (lane == 0) { rmn[wave] = mn; rmx[wave] = mx; }
  __syncthreads();
  mn = fminf(fminf(rmn[0], rmn[1]), fminf(rmn[2], rmn[3]));
  mx = fmaxf(fmaxf(rmx[0], rmx[1]), fmaxf(rmx[2], rmx[3]));
  float sc = 1.0f / (mx - mn + 1e-7f);
  float4* o4 = (float4*)out + (size_t)nc*65536 + (size_t)sub*2048;
  #pragma unroll
  for (int k = 0; k < 8; ++k) {
    float4 v = o4[k*256 + tid];
    v.x = (v.x - mn) * sc; v.y = (v.y - mn) * sc;
    v.z = (v.z - mn) * sc; v.w = (v.w - mn) * sc;
    o4[k*256 + tid] = v;
  }
}

extern "C" void kernel_launch(void* const* d_in, const int* in_sizes, int n_in,
                              void* d_out, int out_size, void* d_ws, size_t ws_size,
                              hipStream_t stream) {
  const float* x  = (const float*)d_in[0];
  const float* o1 = (const float*)d_in[1];
  const float* o2 = (const float*)d_in[2];
  float* out = (float*)d_out;
  float* wsf = (float*)d_ws;
  unsigned* hist = (unsigned*)(out + (size_t)16*HW);   // d_out scratch (atomics OK)

  k_zero<<<dim3(64), dim3(256), 0, stream>>>(hist);
  k_dark<<<dim3(8, 16, 16), dim3(256), 0, stream>>>(x, wsf, hist);
  k_sel<<<dim3(16), dim3(256), 0, stream>>>(hist, wsf, o1, o2);
  k_main<<<dim3(8, 32, 16), dim3(256), 0, stream>>>(x, wsf, out);
  k_norm<<<dim3(1536), dim3(256), 0, stream>>>(out, wsf);
}

// Round 10
// 186.768 us; speedup vs baseline: 1.4074x; 1.4074x over previous
//
#include <hip/hip_runtime.h>
#include <math.h>

#define NS   16
#define HH   512
#define WW   512
#define HW   (HH*WW)
#define TOPK 13107
#define NBIN 4096

// ---- ws word offsets. NO ATOMICS EVER TARGET d_ws (measured 100+us stalls r1/r2).
// ---- NO cooperative/persistent kernel (measured 1.1ms effective 263 GB/s, r5).
// ---- NO ballot-leader aggregation for smooth value-domain bins (r6: 157us k_dark).
// ---- NO multi-word/float same-address LDS atomics per pixel (r9: 125us k_dark).
// ---- Dispatch boundaries ~2us each; count-only LDS hist atomic is fine (r4/r8).
#define O_O1   0        // [16][7] squashed o1 params   (written k_asum, read k_main)
#define O_O2   112      // [16][4] softmax weights
#define O_DEN  176      // [16]    sum(o2)+0.001
#define O_KN   304      // [16]    remaining k within threshold bin
#define O_MMP  512      // [48][512] per-tile min(0:256)/max(256:512) partials
#define O_PART 25088    // [1024][8] asum per-block partials (plain stores only)
#define O_DARK 33280    // [16*512*512] f32 dark channel

// ---- d_out scratch (words; consumed by k_asum before k_main overwrites out):
//   hist = out + 16HW  (16x4096 u32; atomics OK here — d_out, measured fast r2-r4)

// Gaussian weights phi/(sum+0.001), hardcoded (double-derived; ref fp32 diff ~1e-8)
#define G0 0.054466787f
#define G1 0.244103071f
#define G2 0.402457854f

__device__ __forceinline__ float tanh01(float v) { return tanhf(v)*0.5f + 0.5f; }
__device__ __forceinline__ float clamp01(float v) { return fminf(fmaxf(v, 0.0f), 1.0f); }
__device__ __forceinline__ int dark_bin(float v) {
  int b = (int)(v * (float)NBIN);
  return b > (NBIN-1) ? (NBIN-1) : (b < 0 ? 0 : b);
}

// ---------------- zero histogram ----------------
__global__ void k_zero(unsigned* __restrict__ hist) {
  int i = blockIdx.x * 256 + threadIdx.x;       // 16384 uint4 = 65536 words
  uint4 z; z.x = 0u; z.y = 0u; z.z = 0u; z.w = 0u;
  ((uint4*)hist)[i] = z;
}

// ---------------- fused minc + 15x15 box filter + count histogram ----------------
// block: 64x32 dark tile. grid (8,16,16).
__global__ void __launch_bounds__(256)
k_dark(const float* __restrict__ x, float* __restrict__ wsf, unsigned* __restrict__ hist) {
  __shared__ __align__(16) float sm[4096 + 46*64];   // union(minc[3680], lh[4096]) + hsum[2944]
  float* minc = sm;
  unsigned* lh = (unsigned*)sm;
  float* hsum = sm + 4096;
  int tid = threadIdx.x;
  int w0 = blockIdx.x * 64, h0 = blockIdx.y * 32, n = blockIdx.z;
  const float* xb = x + (size_t)n*3*HW;

  // stage minc rows [h0-7,h0+39) cols [w0-8,w0+72), zero outside (box filter zero-pads)
  bool interior = (w0 >= 8) && (w0 + 72 <= WW) && (h0 >= 7) && (h0 + 39 <= HH);
  if (interior) {
    for (int i = tid; i < 46*20; i += 256) {
      int r = i / 20, q = i - r*20;
      size_t o = (size_t)(h0 - 7 + r)*WW + (w0 - 8 + 4*q);
      float4 a = *(const float4*)&xb[o];
      float4 b = *(const float4*)&xb[HW + o];
      float4 c = *(const float4*)&xb[2*HW + o];
      float4 v;
      v.x = fminf(fminf(a.x,b.x),c.x); v.y = fminf(fminf(a.y,b.y),c.y);
      v.z = fminf(fminf(a.z,b.z),c.z); v.w = fminf(fminf(a.w,b.w),c.w);
      *(float4*)&minc[r*80 + 4*q] = v;
    }
  } else {
    for (int i = tid; i < 46*20; i += 256) {
      int r = i / 20, q = i - r*20;
      int hm = h0 - 7 + r, wc = w0 - 8 + 4*q;
      float4 v; v.x = 0.f; v.y = 0.f; v.z = 0.f; v.w = 0.f;
      if (hm >= 0 && hm < HH && wc >= 0 && wc < WW) {
        size_t o = (size_t)hm*WW + wc;
        float4 a = *(const float4*)&xb[o];
        float4 b = *(const float4*)&xb[HW + o];
        float4 c = *(const float4*)&xb[2*HW + o];
        v.x = fminf(fminf(a.x,b.x),c.x); v.y = fminf(fminf(a.y,b.y),c.y);
        v.z = fminf(fminf(a.z,b.z),c.z); v.w = fminf(fminf(a.w,b.w),c.w);
      }
      *(float4*)&minc[r*80 + 4*q] = v;
    }
  }
  __syncthreads();
  // horizontal 15-tap sum
  for (int i = tid; i < 46*16; i += 256) {
    int r = i >> 4, c4 = (i & 15) * 4;
    const float4* mr = (const float4*)&minc[r*80];
    int qb = c4 >> 2;
    float m[20];
    #pragma unroll
    for (int t = 0; t < 5; ++t) {
      float4 v = mr[qb + t];
      m[4*t] = v.x; m[4*t+1] = v.y; m[4*t+2] = v.z; m[4*t+3] = v.w;
    }
    float s = 0.f;
    #pragma unroll
    for (int j = 1; j <= 15; ++j) s += m[j];
    float4 o;
    o.x = s; s += m[16] - m[1];
    o.y = s; s += m[17] - m[2];
    o.z = s; s += m[18] - m[3];
    o.w = s;
    *(float4*)&hsum[r*64 + c4] = o;
  }
  __syncthreads();
  for (int i = tid; i < NBIN; i += 256) lh[i] = 0u;   // minc dead; reuse as hist
  __syncthreads();
  // vertical 15-tap sliding sum -> dark; count-only per-pixel LDS atomic (r4/r8-proven)
  {
    int c = tid & 63, ty = tid >> 6, r0 = ty * 8;
    float s = 0.f;
    #pragma unroll
    for (int j = 0; j < 15; ++j) s += hsum[(r0 + j)*64 + c];
    float* dk = wsf + O_DARK + (size_t)n*HW;
    #pragma unroll
    for (int i = 0; i < 8; ++i) {
      int r = r0 + i;
      float v = s * (1.0f/225.0f);
      dk[(size_t)(h0 + r)*WW + w0 + c] = v;
      atomicAdd(&lh[dark_bin(v)], 1u);
      if (i < 7) s += hsum[(r + 15)*64 + c] - hsum[r*64 + c];
    }
  }
  __syncthreads();
  unsigned* gh = hist + n*NBIN;
  for (int i = tid; i < NBIN; i += 256) { unsigned v = lh[i]; if (v) atomicAdd(&gh[i], v); }
}

// ---------------- fused select head + atmospheric partial sums + params ----------------
__global__ void __launch_bounds__(256)
k_asum(const float* __restrict__ x, float* __restrict__ wsf,
       const unsigned* __restrict__ hist, unsigned* __restrict__ wsu,
       const float* __restrict__ o1, const float* __restrict__ o2) {
  __shared__ __align__(16) unsigned lh[NBIN];
  __shared__ unsigned spp[256];
  __shared__ int sh_bsel;
  __shared__ float bl[4][7];
  int tid = threadIdx.x;
  int n = blockIdx.x >> 6, chunk = blockIdx.x & 63;
  // select head: load hist (L2-hot) + redundant per-block scan (r4/r8-proven ~1us)
  const uint4* gh4 = (const uint4*)(hist + n*NBIN);
  unsigned ps = 0;
  #pragma unroll
  for (int k = 0; k < 4; ++k) {
    uint4 v = gh4[tid*4 + k];
    *(uint4*)&lh[tid*16 + 4*k] = v;
    ps += v.x + v.y + v.z + v.w;
  }
  spp[tid] = ps;
  __syncthreads();
  if (tid == 0) {
    const unsigned K = TOPK;
    unsigned cum = 0; int bsel = 0;
    for (int t = 255; t >= 0; --t) {
      if (cum + spp[t] >= K) {
        bsel = t*16;
        for (int b = t*16 + 15; b >= t*16; --b) {
          if (cum + lh[b] >= K) { bsel = b; break; }
          cum += lh[b];
        }
        break;
      }
      cum += spp[t];
    }
    sh_bsel = bsel;
    if (chunk == 0) {
      wsu[O_KN + n] = K - cum;   // plain store to ws
      // param squashing for this n (single writer; consumed by k_main next dispatch)
      wsf[O_O1+n*7+0] = tanh01(o1[n*7+0])*0.25f + 1.0f;
      wsf[O_O1+n*7+1] = tanh01(o1[n*7+1])*0.9f  + 0.1f;
      wsf[O_O1+n*7+2] = tanh01(o1[n*7+2])*2.0f;
      wsf[O_O1+n*7+3] = tanh01(o1[n*7+3]);
      wsf[O_O1+n*7+4] = tanh01(o1[n*7+4])*0.1f + 0.95f;
      wsf[O_O1+n*7+5] = tanh01(o1[n*7+5])*0.1f + 0.95f;
      wsf[O_O1+n*7+6] = tanh01(o1[n*7+6])*0.1f + 0.95f;
      float q0 = expf(tanh01(o2[n*4+0]));
      float q1 = expf(tanh01(o2[n*4+1]));
      float q2 = expf(tanh01(o2[n*4+2]));
      float q3 = expf(tanh01(o2[n*4+3]));
      float s = q0+q1+q2+q3;
      q0 /= s; q1 /= s; q2 /= s; q3 /= s;
      wsf[O_O2+n*4+0]=q0; wsf[O_O2+n*4+1]=q1; wsf[O_O2+n*4+2]=q2; wsf[O_O2+n*4+3]=q3;
      wsf[O_DEN+n] = (q0+q1+q2+q3) + 0.001f;
    }
  }
  __syncthreads();
  int bsel = sh_bsel;
  // branchless f4 partial sums over this 4096-element chunk
  const float4* db = (const float4*)(wsf + O_DARK + (size_t)n*HW + (size_t)chunk*4096);
  const float4* x0 = (const float4*)(x + (size_t)n*3*HW + (size_t)chunk*4096);
  const float4* x1 = x0 + HW/4;
  const float4* x2 = x0 + HW/2;
  float s0=0,s1=0,s2=0,e0=0,e1=0,e2=0,ec=0;
  #pragma unroll
  for (int k = 0; k < 4; ++k) {
    int idx = k*256 + tid;
    float4 d = db[idx], a = x0[idx], b = x1[idx], c = x2[idx];
    #define ACC(DX, AX, BX, CX) { \
      int bb = dark_bin(DX); \
      bool gt = (bb > bsel), eq = (bb == bsel); \
      s0 += gt ? AX : 0.f; s1 += gt ? BX : 0.f; s2 += gt ? CX : 0.f; \
      e0 += eq ? AX : 0.f; e1 += eq ? BX : 0.f; e2 += eq ? CX : 0.f; \
      ec += eq ? 1.f : 0.f; }
    ACC(d.x, a.x, b.x, c.x) ACC(d.y, a.y, b.y, c.y)
    ACC(d.z, a.z, b.z, c.z) ACC(d.w, a.w, b.w, c.w)
    #undef ACC
  }
  #pragma unroll
  for (int off = 32; off; off >>= 1) {
    s0 += __shfl_down(s0, off); s1 += __shfl_down(s1, off); s2 += __shfl_down(s2, off);
    e0 += __shfl_down(e0, off); e1 += __shfl_down(e1, off); e2 += __shfl_down(e2, off);
    ec += __shfl_down(ec, off);
  }
  int wave = tid >> 6, lane = tid & 63;
  if (lane == 0) {
    bl[wave][0]=s0; bl[wave][1]=s1; bl[wave][2]=s2;
    bl[wave][3]=e0; bl[wave][4]=e1; bl[wave][5]=e2; bl[wave][6]=ec;
  }
  __syncthreads();
  if (tid < 7) wsf[O_PART + blockIdx.x*8 + tid] =
      bl[0][tid] + bl[1][tid] + bl[2][tid] + bl[3][tid];   // plain store to ws
}

// ---------------- fused per-pixel kernel: 3 channels per block, A-reduce head ----------------
// grid (8,32,16): 64x16 tile of sample n; dark read once; channels 0..2 sequential.
__global__ void __launch_bounds__(256)
k_main(const float* __restrict__ x, float* __restrict__ wsf,
       const unsigned* __restrict__ wsu, float* __restrict__ out) {
  __shared__ __align__(16) float xs[20*72];   // rows h0-2..h0+17, cols w0-4..w0+67
  __shared__ __align__(16) float hb[20*64];   // horizontal blur
  __shared__ float rmn[4], rmx[4];
  __shared__ float shA[3];
  int tid = threadIdx.x;
  int w0 = blockIdx.x * 64, h0 = blockIdx.y * 16, n = blockIdx.z;
  int r = tid >> 4, c4 = (tid & 15) * 4;
  int wave = tid >> 6, lane = tid & 63;
  int bxy = blockIdx.y * 8 + blockIdx.x;
  float4 dk = *(const float4*)&wsf[O_DARK + (size_t)n*HW + (size_t)(h0+r)*WW + w0 + c4];
  float param = wsf[O_O1 + n*7 + 0];
  float lamda = wsf[O_O1 + n*7 + 2];
  float wpar  = wsf[O_O1 + n*7 + 3];
  float q0 = wsf[O_O2 + n*4 + 0], q1 = wsf[O_O2 + n*4 + 1];
  float q2 = wsf[O_O2 + n*4 + 2], q3 = wsf[O_O2 + n*4 + 3];
  float rden = 1.0f / wsf[O_DEN + n];
  bool interior = (w0 >= 4) && (w0 + 68 <= WW) && (h0 >= 2) && (h0 + 18 <= HH);
  // A-reduce head (once per block, all 3 channels; partials from previous dispatch)
  if (tid < 64) {
    const float* p = wsf + O_PART + (size_t)(n*64 + tid)*8;
    float s0=p[0], s1=p[1], s2=p[2], e0=p[3], e1=p[4], e2=p[5], ec=p[6];
    #pragma unroll
    for (int off = 32; off; off >>= 1) {
      s0 += __shfl_down(s0, off); s1 += __shfl_down(s1, off); s2 += __shfl_down(s2, off);
      e0 += __shfl_down(e0, off); e1 += __shfl_down(e1, off); e2 += __shfl_down(e2, off);
      ec += __shfl_down(ec, off);
    }
    if (tid == 0) {
      float kn = (float)wsu[O_KN + n];
      float ce = fmaxf(ec, 1.0f);
      shA[0] = (s0 + kn * (e0 / ce)) * (1.0f/(float)TOPK);
      shA[1] = (s1 + kn * (e1 / ce)) * (1.0f/(float)TOPK);
      shA[2] = (s2 + kn * (e2 / ce)) * (1.0f/(float)TOPK);
    }
  }

  for (int c = 0; c < 3; ++c) {
    int z = n*3 + c;
    const float* xc = x + (size_t)z*HW;
    if (interior) {
      for (int i = tid; i < 360; i += 256) {
        int rr = i / 18, q = i - rr*18;
        *(float4*)&xs[rr*72 + 4*q] =
            *(const float4*)&xc[(size_t)(h0 - 2 + rr)*WW + (w0 - 4 + 4*q)];
      }
    } else {
      for (int i = tid; i < 360; i += 256) {
        int rr = i / 18, q = i - rr*18;
        int gh = h0 - 2 + rr, gw = w0 - 4 + 4*q;
        float4 v; v.x = 0.f; v.y = 0.f; v.z = 0.f; v.w = 0.f;
        if (gh >= 0 && gh < HH && gw >= 0 && gw < WW)
          v = *(const float4*)&xc[(size_t)gh*WW + gw];
        *(float4*)&xs[rr*72 + 4*q] = v;
      }
    }
    __syncthreads();   // xs staged; also covers shA write on first iteration
    for (int i = tid; i < 320; i += 256) {
      int rr = i >> 4, cc4 = (i & 15) * 4;
      const float4* xr = (const float4*)&xs[rr*72];
      int qb = cc4 >> 2;
      float4 A4 = xr[qb], B4 = xr[qb+1], C4 = xr[qb+2];
      float m2=A4.z, m3=A4.w, m4=B4.x, m5=B4.y, m6=B4.z, m7=B4.w, m8=C4.x, m9=C4.y;
      float4 o;
      o.x = G0*(m2+m6) + G1*(m3+m5) + G2*m4;
      o.y = G0*(m3+m7) + G1*(m4+m6) + G2*m5;
      o.z = G0*(m4+m8) + G1*(m5+m7) + G2*m6;
      o.w = G0*(m5+m9) + G1*(m6+m8) + G2*m7;
      *(float4*)&hb[rr*64 + cc4] = o;
    }
    __syncthreads();
    float wb = wsf[O_O1 + n*7 + 4 + c];
    float A  = shA[c];
    float4 xv = *(const float4*)&xs[(r+2)*72 + c4 + 4];
    float4 b0 = *(const float4*)&hb[(r+0)*64 + c4];
    float4 b1 = *(const float4*)&hb[(r+1)*64 + c4];
    float4 b2 = *(const float4*)&hb[(r+2)*64 + c4];
    float4 b3 = *(const float4*)&hb[(r+3)*64 + c4];
    float4 b4 = *(const float4*)&hb[(r+4)*64 + c4];
    float4 osum;
    float mnv = 3.4e38f, mxv = -3.4e38f;
    #define PIX(OX, XV, B0, B1, B2, B3, B4, DK) { \
      float blur = clamp01(G0*(B0+B4) + G1*(B1+B3) + G2*B2); \
      float x4v = clamp01(XV + lamda*(XV - blur)); \
      float x1v = clamp01(XV * wb); \
      float x2v = clamp01(__expf(param*__logf(XV)) + 0.001f); \
      float tr = 1.0f - wpar*DK; tr = tr > 0.1f ? tr : 0.1f; \
      float x5v = clamp01((XV - A) * __builtin_amdgcn_rcpf(tr + 0.001f) + A); \
      OX = (XV + 0.1f*(q0*x1v + q1*x2v + q2*x4v + q3*x5v)) * rden; \
      mnv = fminf(mnv, OX); mxv = fmaxf(mxv, OX); }
    PIX(osum.x, xv.x, b0.x, b1.x, b2.x, b3.x, b4.x, dk.x)
    PIX(osum.y, xv.y, b0.y, b1.y, b2.y, b3.y, b4.y, dk.y)
    PIX(osum.z, xv.z, b0.z, b1.z, b2.z, b3.z, b4.z, dk.z)
    PIX(osum.w, xv.w, b0.w, b1.w, b2.w, b3.w, b4.w, dk.w)
    #undef PIX
    *(float4*)&out[(size_t)z*HW + (size_t)(h0+r)*WW + w0 + c4] = osum;
    #pragma unroll
    for (int off = 32; off; off >>= 1) {
      mnv = fminf(mnv, __shfl_down(mnv, off));
      mxv = fmaxf(mxv, __shfl_down(mxv, off));
    }
    if (lane == 0) { rmn[wave] = mnv; rmx[wave] = mxv; }
    __syncthreads();   // also protects xs/hb reuse next channel
    if (tid == 0) {
      mnv = fminf(fminf(rmn[0], rmn[1]), fminf(rmn[2], rmn[3]));
      mxv = fmaxf(fmaxf(rmx[0], rmx[1]), fmaxf(rmx[2], rmx[3]));
      wsf[O_MMP + z*512 + bxy]       = mnv;   // plain stores to ws
      wsf[O_MMP + z*512 + 256 + bxy] = mxv;
    }
  }
}

// ---------------- fused min/max fold head + streaming normalization ----------------
__global__ void __launch_bounds__(256)
k_norm(float* __restrict__ out, const float* __restrict__ wsf) {
  __shared__ float rmn[4], rmx[4];
  int tid = threadIdx.x;
  int nc = blockIdx.x >> 5;          // 32 blocks per (n,c), 2048 f4 each
  int sub = blockIdx.x & 31;
  float mn = wsf[O_MMP + nc*512 + tid];
  float mx = wsf[O_MMP + nc*512 + 256 + tid];
  #pragma unroll
  for (int off = 32; off; off >>= 1) {
    mn = fminf(mn, __shfl_down(mn, off));
    mx = fmaxf(mx, __shfl_down(mx, off));
  }
  int wave = tid >> 6, lane = tid & 63;
  if (lane == 0) { rmn[wave] = mn; rmx[wave] = mx; }
  __syncthreads();
  mn = fminf(fminf(rmn[0], rmn[1]), fminf(rmn[2], rmn[3]));
  mx = fmaxf(fmaxf(rmx[0], rmx[1]), fmaxf(rmx[2], rmx[3]));
  float sc = 1.0f / (mx - mn + 1e-7f);
  float4* o4 = (float4*)out + (size_t)nc*65536 + (size_t)sub*2048;
  #pragma unroll
  for (int k = 0; k < 8; ++k) {
    float4 v = o4[k*256 + tid];
    v.x = (v.x - mn) * sc; v.y = (v.y - mn) * sc;
    v.z = (v.z - mn) * sc; v.w = (v.w - mn) * sc;
    o4[k*256 + tid] = v;
  }
}

extern "C" void kernel_launch(void* const* d_in, const int* in_sizes, int n_in,
                              void* d_out, int out_size, void* d_ws, size_t ws_size,
                              hipStream_t stream) {
  const float* x  = (const float*)d_in[0];
  const float* o1 = (const float*)d_in[1];
  const float* o2 = (const float*)d_in[2];
  float* out = (float*)d_out;
  float* wsf = (float*)d_ws;
  unsigned* wsu = (unsigned*)d_ws;
  unsigned* hist = (unsigned*)(out + (size_t)16*HW);   // d_out scratch (atomics OK)

  k_zero<<<dim3(64), dim3(256), 0, stream>>>(hist);
  k_dark<<<dim3(8, 16, 16), dim3(256), 0, stream>>>(x, wsf, hist);
  k_asum<<<dim3(1024), dim3(256), 0, stream>>>(x, wsf, hist, wsu, o1, o2);
  k_main<<<dim3(8, 32, 16), dim3(256), 0, stream>>>(x, wsf, wsu, out);
  k_norm<<<dim3(1536), dim3(256), 0, stream>>>(out, wsf);
}

// Round 11
// 177.089 us; speedup vs baseline: 1.4843x; 1.0547x over previous
//
#include <hip/hip_runtime.h>
#include <math.h>

#define NS   16
#define HH   512
#define WW   512
#define HW   (HH*WW)
#define TOPK 13107
#define NBIN 1024

// ---- ws word offsets. NO ATOMICS EVER TARGET d_ws (measured 100+us stalls r1/r2).
// ---- NO cooperative/persistent kernel (measured 1.1ms effective 263 GB/s, r5).
// ---- NO ballot-leader aggregation for smooth value-domain bins (r6: 157us k_dark).
// ---- NO multi-word/float same-address LDS atomics per pixel (r9: 125us k_dark).
// ---- Same-address LDS atomic serialization mitigated via 4 lane-interleaved
//      replicas + vertical run-length (register-only, no cross-lane ops).
#define O_O1   0        // [16][7] squashed o1 params   (written k_asum, read k_main)
#define O_O2   112      // [16][4] softmax weights
#define O_DEN  176      // [16]    sum(o2)+0.001
#define O_KN   304      // [16]    remaining k within threshold bin
#define O_MMP  512      // [48][512] per-tile min(0:256)/max(256:512) partials
#define O_PART 25088    // [1024][8] asum per-block partials (plain stores only)
#define O_DARK 33280    // [16*512*512] f32 dark channel

// ---- d_out scratch (words; consumed by k_asum before k_main overwrites out):
//   hist = out + 16HW  (16x1024 u32; atomics OK here — d_out, measured fast r2-r4)

// Gaussian weights phi/(sum+0.001), hardcoded (double-derived; ref fp32 diff ~1e-8)
#define G0 0.054466787f
#define G1 0.244103071f
#define G2 0.402457854f

__device__ __forceinline__ float tanh01(float v) { return tanhf(v)*0.5f + 0.5f; }
__device__ __forceinline__ float clamp01(float v) { return fminf(fmaxf(v, 0.0f), 1.0f); }
__device__ __forceinline__ int dark_bin(float v) {
  int b = (int)(v * (float)NBIN);
  return b > (NBIN-1) ? (NBIN-1) : (b < 0 ? 0 : b);
}

// ---------------- zero histogram (16*1024 words = 4096 uint4) ----------------
__global__ void k_zero(unsigned* __restrict__ hist) {
  int i = blockIdx.x * 256 + threadIdx.x;
  uint4 z; z.x = 0u; z.y = 0u; z.z = 0u; z.w = 0u;
  ((uint4*)hist)[i] = z;
}

// ---------------- fused minc + 15x15 box filter + count histogram ----------------
// block: 64x32 dark tile. grid (8,16,16).
__global__ void __launch_bounds__(256)
k_dark(const float* __restrict__ x, float* __restrict__ wsf, unsigned* __restrict__ hist) {
  __shared__ __align__(16) float sm[4096 + 46*64];   // union(minc[3680], lh[1024*4 replicas]) + hsum[2944]
  float* minc = sm;
  unsigned* lh = (unsigned*)sm;     // [1024 bins][4 replicas] interleaved
  float* hsum = sm + 4096;
  int tid = threadIdx.x;
  int w0 = blockIdx.x * 64, h0 = blockIdx.y * 32, n = blockIdx.z;
  const float* xb = x + (size_t)n*3*HW;

  // stage minc rows [h0-7,h0+39) cols [w0-8,w0+72), zero outside (box filter zero-pads)
  bool interior = (w0 >= 8) && (w0 + 72 <= WW) && (h0 >= 7) && (h0 + 39 <= HH);
  if (interior) {
    for (int i = tid; i < 46*20; i += 256) {
      int r = i / 20, q = i - r*20;
      size_t o = (size_t)(h0 - 7 + r)*WW + (w0 - 8 + 4*q);
      float4 a = *(const float4*)&xb[o];
      float4 b = *(const float4*)&xb[HW + o];
      float4 c = *(const float4*)&xb[2*HW + o];
      float4 v;
      v.x = fminf(fminf(a.x,b.x),c.x); v.y = fminf(fminf(a.y,b.y),c.y);
      v.z = fminf(fminf(a.z,b.z),c.z); v.w = fminf(fminf(a.w,b.w),c.w);
      *(float4*)&minc[r*80 + 4*q] = v;
    }
  } else {
    for (int i = tid; i < 46*20; i += 256) {
      int r = i / 20, q = i - r*20;
      int hm = h0 - 7 + r, wc = w0 - 8 + 4*q;
      float4 v; v.x = 0.f; v.y = 0.f; v.z = 0.f; v.w = 0.f;
      if (hm >= 0 && hm < HH && wc >= 0 && wc < WW) {
        size_t o = (size_t)hm*WW + wc;
        float4 a = *(const float4*)&xb[o];
        float4 b = *(const float4*)&xb[HW + o];
        float4 c = *(const float4*)&xb[2*HW + o];
        v.x = fminf(fminf(a.x,b.x),c.x); v.y = fminf(fminf(a.y,b.y),c.y);
        v.z = fminf(fminf(a.z,b.z),c.z); v.w = fminf(fminf(a.w,b.w),c.w);
      }
      *(float4*)&minc[r*80 + 4*q] = v;
    }
  }
  __syncthreads();
  // horizontal 15-tap sum
  for (int i = tid; i < 46*16; i += 256) {
    int r = i >> 4, c4 = (i & 15) * 4;
    const float4* mr = (const float4*)&minc[r*80];
    int qb = c4 >> 2;
    float m[20];
    #pragma unroll
    for (int t = 0; t < 5; ++t) {
      float4 v = mr[qb + t];
      m[4*t] = v.x; m[4*t+1] = v.y; m[4*t+2] = v.z; m[4*t+3] = v.w;
    }
    float s = 0.f;
    #pragma unroll
    for (int j = 1; j <= 15; ++j) s += m[j];
    float4 o;
    o.x = s; s += m[16] - m[1];
    o.y = s; s += m[17] - m[2];
    o.z = s; s += m[18] - m[3];
    o.w = s;
    *(float4*)&hsum[r*64 + c4] = o;
  }
  __syncthreads();
  for (int i = tid; i < NBIN*4; i += 256) lh[i] = 0u;   // minc dead; reuse as hist
  __syncthreads();
  // vertical 15-tap sliding sum -> dark; run-length + 4-replica LDS atomics
  {
    int c = tid & 63, ty = tid >> 6, r0 = ty * 8;
    int rep = tid & 3;
    float s = 0.f;
    #pragma unroll
    for (int j = 0; j < 15; ++j) s += hsum[(r0 + j)*64 + c];
    float* dk = wsf + O_DARK + (size_t)n*HW;
    int prevb = -1; unsigned cnt = 0;
    #pragma unroll
    for (int i = 0; i < 8; ++i) {
      int r = r0 + i;
      float v = s * (1.0f/225.0f);
      dk[(size_t)(h0 + r)*WW + w0 + c] = v;
      int b = dark_bin(v);
      if (b == prevb) { cnt++; }
      else {
        if (cnt) atomicAdd(&lh[(prevb << 2) | rep], cnt);
        prevb = b; cnt = 1u;
      }
      if (i < 7) s += hsum[(r + 15)*64 + c] - hsum[r*64 + c];
    }
    atomicAdd(&lh[(prevb << 2) | rep], cnt);
  }
  __syncthreads();
  unsigned* gh = hist + n*NBIN;
  for (int b = tid; b < NBIN; b += 256) {
    unsigned v = lh[4*b] + lh[4*b+1] + lh[4*b+2] + lh[4*b+3];
    if (v) atomicAdd(&gh[b], v);
  }
}

// ---------------- fused select head + atmospheric partial sums + params ----------------
__global__ void __launch_bounds__(256)
k_asum(const float* __restrict__ x, float* __restrict__ wsf,
       const unsigned* __restrict__ hist, unsigned* __restrict__ wsu,
       const float* __restrict__ o1, const float* __restrict__ o2) {
  __shared__ __align__(16) unsigned lh[NBIN];
  __shared__ unsigned spp[256];
  __shared__ int sh_bsel;
  __shared__ float bl[4][7];
  int tid = threadIdx.x;
  int n = blockIdx.x >> 6, chunk = blockIdx.x & 63;
  // select head: load hist (L2-hot) + redundant per-block scan (r4/r8-proven ~1us)
  {
    uint4 v = ((const uint4*)(hist + n*NBIN))[tid];   // 4 bins per thread
    *(uint4*)&lh[tid*4] = v;
    spp[tid] = v.x + v.y + v.z + v.w;
  }
  __syncthreads();
  if (tid == 0) {
    const unsigned K = TOPK;
    unsigned cum = 0; int bsel = 0;
    for (int t = 255; t >= 0; --t) {
      if (cum + spp[t] >= K) {
        bsel = t*4;
        for (int b = t*4 + 3; b >= t*4; --b) {
          if (cum + lh[b] >= K) { bsel = b; break; }
          cum += lh[b];
        }
        break;
      }
      cum += spp[t];
    }
    sh_bsel = bsel;
    if (chunk == 0) {
      wsu[O_KN + n] = K - cum;   // plain store to ws
      // param squashing for this n (single writer; consumed by k_main next dispatch)
      wsf[O_O1+n*7+0] = tanh01(o1[n*7+0])*0.25f + 1.0f;
      wsf[O_O1+n*7+1] = tanh01(o1[n*7+1])*0.9f  + 0.1f;
      wsf[O_O1+n*7+2] = tanh01(o1[n*7+2])*2.0f;
      wsf[O_O1+n*7+3] = tanh01(o1[n*7+3]);
      wsf[O_O1+n*7+4] = tanh01(o1[n*7+4])*0.1f + 0.95f;
      wsf[O_O1+n*7+5] = tanh01(o1[n*7+5])*0.1f + 0.95f;
      wsf[O_O1+n*7+6] = tanh01(o1[n*7+6])*0.1f + 0.95f;
      float q0 = expf(tanh01(o2[n*4+0]));
      float q1 = expf(tanh01(o2[n*4+1]));
      float q2 = expf(tanh01(o2[n*4+2]));
      float q3 = expf(tanh01(o2[n*4+3]));
      float s = q0+q1+q2+q3;
      q0 /= s; q1 /= s; q2 /= s; q3 /= s;
      wsf[O_O2+n*4+0]=q0; wsf[O_O2+n*4+1]=q1; wsf[O_O2+n*4+2]=q2; wsf[O_O2+n*4+3]=q3;
      wsf[O_DEN+n] = (q0+q1+q2+q3) + 0.001f;
    }
  }
  __syncthreads();
  int bsel = sh_bsel;
  // branchless f4 partial sums over this 4096-element chunk
  const float4* db = (const float4*)(wsf + O_DARK + (size_t)n*HW + (size_t)chunk*4096);
  const float4* x0 = (const float4*)(x + (size_t)n*3*HW + (size_t)chunk*4096);
  const float4* x1 = x0 + HW/4;
  const float4* x2 = x0 + HW/2;
  float s0=0,s1=0,s2=0,e0=0,e1=0,e2=0,ec=0;
  #pragma unroll
  for (int k = 0; k < 4; ++k) {
    int idx = k*256 + tid;
    float4 d = db[idx], a = x0[idx], b = x1[idx], c = x2[idx];
    #define ACC(DX, AX, BX, CX) { \
      int bb = dark_bin(DX); \
      bool gt = (bb > bsel), eq = (bb == bsel); \
      s0 += gt ? AX : 0.f; s1 += gt ? BX : 0.f; s2 += gt ? CX : 0.f; \
      e0 += eq ? AX : 0.f; e1 += eq ? BX : 0.f; e2 += eq ? CX : 0.f; \
      ec += eq ? 1.f : 0.f; }
    ACC(d.x, a.x, b.x, c.x) ACC(d.y, a.y, b.y, c.y)
    ACC(d.z, a.z, b.z, c.z) ACC(d.w, a.w, b.w, c.w)
    #undef ACC
  }
  #pragma unroll
  for (int off = 32; off; off >>= 1) {
    s0 += __shfl_down(s0, off); s1 += __shfl_down(s1, off); s2 += __shfl_down(s2, off);
    e0 += __shfl_down(e0, off); e1 += __shfl_down(e1, off); e2 += __shfl_down(e2, off);
    ec += __shfl_down(ec, off);
  }
  int wave = tid >> 6, lane = tid & 63;
  if (lane == 0) {
    bl[wave][0]=s0; bl[wave][1]=s1; bl[wave][2]=s2;
    bl[wave][3]=e0; bl[wave][4]=e1; bl[wave][5]=e2; bl[wave][6]=ec;
  }
  __syncthreads();
  if (tid < 7) wsf[O_PART + blockIdx.x*8 + tid] =
      bl[0][tid] + bl[1][tid] + bl[2][tid] + bl[3][tid];   // plain store to ws
}

// ---------------- fused per-pixel kernel: 3 channels per block, A-reduce head ----------------
// grid (8,32,16): 64x16 tile of sample n; dark read once; channels 0..2 sequential.
__global__ void __launch_bounds__(256)
k_main(const float* __restrict__ x, float* __restrict__ wsf,
       const unsigned* __restrict__ wsu, float* __restrict__ out) {
  __shared__ __align__(16) float xs[20*72];   // rows h0-2..h0+17, cols w0-4..w0+67
  __shared__ __align__(16) float hb[20*64];   // horizontal blur
  __shared__ float rmn[4], rmx[4];
  __shared__ float shA[3];
  int tid = threadIdx.x;
  int w0 = blockIdx.x * 64, h0 = blockIdx.y * 16, n = blockIdx.z;
  int r = tid >> 4, c4 = (tid & 15) * 4;
  int wave = tid >> 6, lane = tid & 63;
  int bxy = blockIdx.y * 8 + blockIdx.x;
  float4 dk = *(const float4*)&wsf[O_DARK + (size_t)n*HW + (size_t)(h0+r)*WW + w0 + c4];
  float param = wsf[O_O1 + n*7 + 0];
  float lamda = wsf[O_O1 + n*7 + 2];
  float wpar  = wsf[O_O1 + n*7 + 3];
  float q0 = wsf[O_O2 + n*4 + 0], q1 = wsf[O_O2 + n*4 + 1];
  float q2 = wsf[O_O2 + n*4 + 2], q3 = wsf[O_O2 + n*4 + 3];
  float rden = 1.0f / wsf[O_DEN + n];
  bool interior = (w0 >= 4) && (w0 + 68 <= WW) && (h0 >= 2) && (h0 + 18 <= HH);
  // A-reduce head (once per block, all 3 channels; partials from previous dispatch)
  if (tid < 64) {
    const float* p = wsf + O_PART + (size_t)(n*64 + tid)*8;
    float s0=p[0], s1=p[1], s2=p[2], e0=p[3], e1=p[4], e2=p[5], ec=p[6];
    #pragma unroll
    for (int off = 32; off; off >>= 1) {
      s0 += __shfl_down(s0, off); s1 += __shfl_down(s1, off); s2 += __shfl_down(s2, off);
      e0 += __shfl_down(e0, off); e1 += __shfl_down(e1, off); e2 += __shfl_down(e2, off);
      ec += __shfl_down(ec, off);
    }
    if (tid == 0) {
      float kn = (float)wsu[O_KN + n];
      float ce = fmaxf(ec, 1.0f);
      shA[0] = (s0 + kn * (e0 / ce)) * (1.0f/(float)TOPK);
      shA[1] = (s1 + kn * (e1 / ce)) * (1.0f/(float)TOPK);
      shA[2] = (s2 + kn * (e2 / ce)) * (1.0f/(float)TOPK);
    }
  }

  for (int c = 0; c < 3; ++c) {
    int z = n*3 + c;
    const float* xc = x + (size_t)z*HW;
    if (interior) {
      for (int i = tid; i < 360; i += 256) {
        int rr = i / 18, q = i - rr*18;
        *(float4*)&xs[rr*72 + 4*q] =
            *(const float4*)&xc[(size_t)(h0 - 2 + rr)*WW + (w0 - 4 + 4*q)];
      }
    } else {
      for (int i = tid; i < 360; i += 256) {
        int rr = i / 18, q = i - rr*18;
        int gh = h0 - 2 + rr, gw = w0 - 4 + 4*q;
        float4 v; v.x = 0.f; v.y = 0.f; v.z = 0.f; v.w = 0.f;
        if (gh >= 0 && gh < HH && gw >= 0 && gw < WW)
          v = *(const float4*)&xc[(size_t)gh*WW + gw];
        *(float4*)&xs[rr*72 + 4*q] = v;
      }
    }
    __syncthreads();   // xs staged; also covers shA write on first iteration
    for (int i = tid; i < 320; i += 256) {
      int rr = i >> 4, cc4 = (i & 15) * 4;
      const float4* xr = (const float4*)&xs[rr*72];
      int qb = cc4 >> 2;
      float4 A4 = xr[qb], B4 = xr[qb+1], C4 = xr[qb+2];
      float m2=A4.z, m3=A4.w, m4=B4.x, m5=B4.y, m6=B4.z, m7=B4.w, m8=C4.x, m9=C4.y;
      float4 o;
      o.x = G0*(m2+m6) + G1*(m3+m5) + G2*m4;
      o.y = G0*(m3+m7) + G1*(m4+m6) + G2*m5;
      o.z = G0*(m4+m8) + G1*(m5+m7) + G2*m6;
      o.w = G0*(m5+m9) + G1*(m6+m8) + G2*m7;
      *(float4*)&hb[rr*64 + cc4] = o;
    }
    __syncthreads();
    float wb = wsf[O_O1 + n*7 + 4 + c];
    float A  = shA[c];
    float4 xv = *(const float4*)&xs[(r+2)*72 + c4 + 4];
    float4 b0 = *(const float4*)&hb[(r+0)*64 + c4];
    float4 b1 = *(const float4*)&hb[(r+1)*64 + c4];
    float4 b2 = *(const float4*)&hb[(r+2)*64 + c4];
    float4 b3 = *(const float4*)&hb[(r+3)*64 + c4];
    float4 b4 = *(const float4*)&hb[(r+4)*64 + c4];
    float4 osum;
    float mnv = 3.4e38f, mxv = -3.4e38f;
    #define PIX(OX, XV, B0, B1, B2, B3, B4, DK) { \
      float blur = clamp01(G0*(B0+B4) + G1*(B1+B3) + G2*B2); \
      float x4v = clamp01(XV + lamda*(XV - blur)); \
      float x1v = clamp01(XV * wb); \
      float x2v = clamp01(__expf(param*__logf(XV)) + 0.001f); \
      float tr = 1.0f - wpar*DK; tr = tr > 0.1f ? tr : 0.1f; \
      float x5v = clamp01((XV - A) * __builtin_amdgcn_rcpf(tr + 0.001f) + A); \
      OX = (XV + 0.1f*(q0*x1v + q1*x2v + q2*x4v + q3*x5v)) * rden; \
      mnv = fminf(mnv, OX); mxv = fmaxf(mxv, OX); }
    PIX(osum.x, xv.x, b0.x, b1.x, b2.x, b3.x, b4.x, dk.x)
    PIX(osum.y, xv.y, b0.y, b1.y, b2.y, b3.y, b4.y, dk.y)
    PIX(osum.z, xv.z, b0.z, b1.z, b2.z, b3.z, b4.z, dk.z)
    PIX(osum.w, xv.w, b0.w, b1.w, b2.w, b3.w, b4.w, dk.w)
    #undef PIX
    *(float4*)&out[(size_t)z*HW + (size_t)(h0+r)*WW + w0 + c4] = osum;
    #pragma unroll
    for (int off = 32; off; off >>= 1) {
      mnv = fminf(mnv, __shfl_down(mnv, off));
      mxv = fmaxf(mxv, __shfl_down(mxv, off));
    }
    if (lane == 0) { rmn[wave] = mnv; rmx[wave] = mxv; }
    __syncthreads();   // also protects xs/hb reuse next channel
    if (tid == 0) {
      mnv = fminf(fminf(rmn[0], rmn[1]), fminf(rmn[2], rmn[3]));
      mxv = fmaxf(fmaxf(rmx[0], rmx[1]), fmaxf(rmx[2], rmx[3]));
      wsf[O_MMP + z*512 + bxy]       = mnv;   // plain stores to ws
      wsf[O_MMP + z*512 + 256 + bxy] = mxv;
    }
  }
}

// ---------------- fused min/max fold head + streaming normalization ----------------
__global__ void __launch_bounds__(256)
k_norm(float* __restrict__ out, const float* __restrict__ wsf) {
  __shared__ float rmn[4], rmx[4];
  int tid = threadIdx.x;
  int nc = blockIdx.x >> 5;          // 32 blocks per (n,c), 2048 f4 each
  int sub = blockIdx.x & 31;
  float mn = wsf[O_MMP + nc*512 + tid];
  float mx = wsf[O_MMP + nc*512 + 256 + tid];
  #pragma unroll
  for (int off = 32; off; off >>= 1) {
    mn = fminf(mn, __shfl_down(mn, off));
    mx = fmaxf(mx, __shfl_down(mx, off));
  }
  int wave = tid >> 6, lane = tid & 63;
  if (lane == 0) { rmn[wave] = mn; rmx[wave] = mx; }
  __syncthreads();
  mn = fminf(fminf(rmn[0], rmn[1]), fminf(rmn[2], rmn[3]));
  mx = fmaxf(fmaxf(rmx[0], rmx[1]), fmaxf(rmx[2], rmx[3]));
  float sc = 1.0f / (mx - mn + 1e-7f);
  float4* o4 = (float4*)out + (size_t)nc*65536 + (size_t)sub*2048;
  #pragma unroll
  for (int k = 0; k < 8; ++k) {
    float4 v = o4[k*256 + tid];
    v.x = (v.x - mn) * sc; v.y = (v.y - mn) * sc;
    v.z = (v.z - mn) * sc; v.w = (v.w - mn) * sc;
    o4[k*256 + tid] = v;
  }
}

extern "C" void kernel_launch(void* const* d_in, const int* in_sizes, int n_in,
                              void* d_out, int out_size, void* d_ws, size_t ws_size,
                              hipStream_t stream) {
  const float* x  = (const float*)d_in[0];
  const float* o1 = (const float*)d_in[1];
  const float* o2 = (const float*)d_in[2];
  float* out = (float*)d_out;
  float* wsf = (float*)d_ws;
  unsigned* wsu = (unsigned*)d_ws;
  unsigned* hist = (unsigned*)(out + (size_t)16*HW);   // d_out scratch (atomics OK)

  k_zero<<<dim3(16), dim3(256), 0, stream>>>(hist);
  k_dark<<<dim3(8, 16, 16), dim3(256), 0, stream>>>(x, wsf, hist);
  k_asum<<<dim3(1024), dim3(256), 0, stream>>>(x, wsf, hist, wsu, o1, o2);
  k_main<<<dim3(8, 32, 16), dim3(256), 0, stream>>>(x, wsf, wsu, out);
  k_norm<<<dim3(1536), dim3(256), 0, stream>>>(out, wsf);
}